// Round 2
// baseline (178.890 us; speedup 1.0000x reference)
//
#include <hip/hip_runtime.h>
#include <hip/hip_bf16.h>

#define DDIM 1024
#define RREG 36
#define TTOK 64
#define KPAD 48   // attn rows padded 36->48, rows [36,48) written as zero

typedef __attribute__((ext_vector_type(4))) float f32x4;
typedef __attribute__((ext_vector_type(8))) short bf16x8;

__device__ __forceinline__ float sq4(float4 v) {
  return v.x * v.x + v.y * v.y + v.z * v.z + v.w * v.w;
}

__device__ __forceinline__ bf16x8 cvt8(float4 a, float4 b) {
  union { bf16x8 v; __hip_bfloat162 h[4]; } u;
  u.h[0] = __float22bfloat162_rn(make_float2(a.x, a.y));
  u.h[1] = __float22bfloat162_rn(make_float2(a.z, a.w));
  u.h[2] = __float22bfloat162_rn(make_float2(b.x, b.y));
  u.h[3] = __float22bfloat162_rn(make_float2(b.z, b.w));
  return u.v;
}

__device__ __forceinline__ bf16x8 pack8(const float* v) {
  union { bf16x8 x; __hip_bfloat162 h[4]; } u;
#pragma unroll
  for (int i = 0; i < 4; ++i)
    u.h[i] = __float22bfloat162_rn(make_float2(v[2 * i], v[2 * i + 1]));
  return u.x;
}

__device__ __forceinline__ unsigned short f2bf(float x) {
  unsigned int u = __float_as_uint(x);
  u += 0x7fffu + ((u >> 16) & 1u);
  return (unsigned short)(u >> 16);
}

// ---------------- Kernel 1: dots + norms + softmax -> attn^T bf16 ----------------
// grid = B*4 (4 t-tiles of 16), block = 192 (3 waves = 3 r-tiles of 16)
__global__ __launch_bounds__(192) void scan_attn(
    const float* __restrict__ img, const float* __restrict__ cap,
    unsigned short* __restrict__ attnw) {
  __shared__ float sdots[16][52];   // [t-local][r], stride 52 breaks softmax bank aliasing
  __shared__ float sni[KPAD];
  __shared__ float snc[16];

  const int tid  = threadIdx.x;
  const int lane = tid & 63;
  const int wave = tid >> 6;        // r-tile 0..2
  const int fm   = lane & 15;
  const int kq   = lane >> 4;
  const int b    = blockIdx.x >> 2;
  const int t0   = (blockIdx.x & 3) << 4;

  const float* capb = cap + (size_t)b * TTOK * DDIM;
  const float* imgb = img + (size_t)b * RREG * DDIM;

  const int t = t0 + fm;
  const int r = wave * 16 + fm;
  const bool rv = (r < RREG);

  const float* aptr = capb + t * DDIM + kq * 8;
  const float* bptr = imgb + (rv ? r : 0) * DDIM + kq * 8;

  f32x4 acc0 = {0.f, 0.f, 0.f, 0.f}, acc1 = {0.f, 0.f, 0.f, 0.f};
  float cn = 0.f, inrm = 0.f;

#pragma unroll 2
  for (int kc = 0; kc < 16; ++kc) {
    float4 a0 = *(const float4*)(aptr);
    float4 a1 = *(const float4*)(aptr + 4);
    float4 a2 = *(const float4*)(aptr + 32);
    float4 a3 = *(const float4*)(aptr + 36);
    float4 b0 = make_float4(0.f, 0.f, 0.f, 0.f), b1 = b0, b2 = b0, b3 = b0;
    if (rv) {
      b0 = *(const float4*)(bptr);
      b1 = *(const float4*)(bptr + 4);
      b2 = *(const float4*)(bptr + 32);
      b3 = *(const float4*)(bptr + 36);
    }
    aptr += 64; bptr += 64;
    cn   += sq4(a0) + sq4(a1) + sq4(a2) + sq4(a3);
    inrm += sq4(b0) + sq4(b1) + sq4(b2) + sq4(b3);
    acc0 = __builtin_amdgcn_mfma_f32_16x16x32_bf16(cvt8(a0, a1), cvt8(b0, b1), acc0, 0, 0, 0);
    acc1 = __builtin_amdgcn_mfma_f32_16x16x32_bf16(cvt8(a2, a3), cvt8(b2, b3), acc1, 0, 0, 0);
  }
  acc0 += acc1;

  // fold norm partials across the 4 kq groups (lanes fm, fm+16, fm+32, fm+48)
  cn   += __shfl_xor(cn, 16);   cn   += __shfl_xor(cn, 32);
  inrm += __shfl_xor(inrm, 16); inrm += __shfl_xor(inrm, 32);
  if (lane < 16) {
    sni[wave * 16 + fm] = sqrtf(inrm);
    if (wave == 0) snc[fm] = sqrtf(cn);
  }
  // D tile: row(t-local) = kq*4+i, col(r-local) = fm
#pragma unroll
  for (int i = 0; i < 4; ++i)
    sdots[kq * 4 + i][wave * 16 + fm] = acc0[i];
  __syncthreads();

  // softmax over r for 16 tokens; one thread per token
  if (tid < 16) {
    const float cnv = snc[tid];
    float sc[RREG];
    float mx = -1e30f;
#pragma unroll
    for (int rr = 0; rr < RREG; ++rr) {
      float dnm = fmaxf(sni[rr] * cnv, 1e-8f);
      float v = sdots[tid][rr] / dnm;
      sc[rr] = v;
      mx = fmaxf(mx, v);
    }
    float sum = 0.f;
#pragma unroll
    for (int rr = 0; rr < RREG; ++rr) {
      float ev = __expf(sc[rr] - mx);
      sc[rr] = ev;
      sum += ev;
    }
    const float rinv = 1.f / sum;
    unsigned short* arow = attnw + ((size_t)b * TTOK + t0 + tid) * KPAD;
#pragma unroll
    for (int r0 = 0; r0 < RREG; r0 += 4) {
      ushort4 p;
      p.x = f2bf(sc[r0 + 0] * rinv);
      p.y = f2bf(sc[r0 + 1] * rinv);
      p.z = f2bf(sc[r0 + 2] * rinv);
      p.w = f2bf(sc[r0 + 3] * rinv);
      *(ushort4*)(arow + r0) = p;
    }
    ushort4 zz; zz.x = 0; zz.y = 0; zz.z = 0; zz.w = 0;
    *(ushort4*)(arow + 36) = zz;
    *(ushort4*)(arow + 40) = zz;
    *(ushort4*)(arow + 44) = zz;
  }
}

// ---------------- Kernel 2: out = attn^T(64x48) . img(48x1024) ----------------
// grid = B*4 (d-chunks of 256), block = 256 (4 waves = 4 t-tiles); no LDS, no barriers
__global__ __launch_bounds__(256) void scan_out(
    const float* __restrict__ img, const unsigned short* __restrict__ attnw,
    float* __restrict__ out) {
  const int tid  = threadIdx.x;
  const int lane = tid & 63;
  const int wave = tid >> 6;        // t-tile 0..3
  const int fm   = lane & 15;
  const int kq   = lane >> 4;
  const int b    = blockIdx.x >> 2;
  const int d0   = (blockIdx.x & 3) << 8;

  const float* imgb = img + (size_t)b * RREG * DDIM;
  const unsigned short* attb = attnw + (size_t)b * TTOK * KPAD;
  float* outb = out + (size_t)b * TTOK * DDIM;

  // A-frags for this wave's t-tile: k=0..31 and k=32..47 (rest zero)
  const unsigned short* ap = attb + (wave * 16 + fm) * KPAD;
  bf16x8 zf = {0, 0, 0, 0, 0, 0, 0, 0};
  bf16x8 af0 = *(const bf16x8*)(ap + kq * 8);
  bf16x8 af1 = zf;
  if (kq < 2) af1 = *(const bf16x8*)(ap + 32 + kq * 8);

  for (int s = 0; s < 16; ++s) {
    const int d = d0 + s * 16 + fm;
    // B-frag0: k=r=kq*8+j  (all < 32)
    float v[8];
#pragma unroll
    for (int j = 0; j < 8; ++j) v[j] = imgb[(kq * 8 + j) * DDIM + d];
    bf16x8 bf0 = pack8(v);
    // B-frag1: k=32+kq*8+j, valid only r<36 -> kq==0, j<4
    bf16x8 bf1 = zf;
    if (kq == 0) {
      float w[8];
#pragma unroll
      for (int j = 0; j < 4; ++j) w[j] = imgb[(32 + j) * DDIM + d];
#pragma unroll
      for (int j = 4; j < 8; ++j) w[j] = 0.f;
      bf1 = pack8(w);
    }
    f32x4 o = {0.f, 0.f, 0.f, 0.f};
    o = __builtin_amdgcn_mfma_f32_16x16x32_bf16(af0, bf0, o, 0, 0, 0);
    o = __builtin_amdgcn_mfma_f32_16x16x32_bf16(af1, bf1, o, 0, 0, 0);
    float* op = outb + (wave * 16 + kq * 4) * DDIM + d;
#pragma unroll
    for (int i = 0; i < 4; ++i) op[i * DDIM] = o[i];
  }
}

extern "C" void kernel_launch(void* const* d_in, const int* in_sizes, int n_in,
                              void* d_out, int out_size, void* d_ws, size_t ws_size,
                              hipStream_t stream) {
  const float* img = (const float*)d_in[0];   // (256, 36, 1024) fp32
  const float* cap = (const float*)d_in[1];   // (256, 64, 1024) fp32
  float* out = (float*)d_out;                 // (256, 64, 1024) fp32
  unsigned short* attnw = (unsigned short*)d_ws;  // attn^T bf16 [B][64][48] = 1.5 MB

  scan_attn<<<dim3(1024), dim3(192), 0, stream>>>(img, cap, attnw);
  scan_out<<<dim3(1024), dim3(256), 0, stream>>>(img, attnw, out);
}

// Round 3
// 170.147 us; speedup vs baseline: 1.0514x; 1.0514x over previous
//
#include <hip/hip_runtime.h>
#include <hip/hip_bf16.h>

#define DDIM 1024
#define RREG 36
#define TTOK 64
#define KPAD 48    // attn rows padded 36->48, rows [36,48) zero
#define CHUNK 256  // floats per d-chunk in K1
#define LSTR 264   // LDS row stride in shorts: 528 B, 16B-aligned rows, conflict-free b128

typedef __attribute__((ext_vector_type(4))) float f32x4;
typedef __attribute__((ext_vector_type(8))) short bf16x8;

__device__ __forceinline__ float sq4(float4 v) {
  return v.x * v.x + v.y * v.y + v.z * v.z + v.w * v.w;
}

__device__ __forceinline__ ushort4 cvt4(float4 v) {
  union { ushort4 u; __hip_bfloat162 h[2]; } r;
  r.h[0] = __float22bfloat162_rn(make_float2(v.x, v.y));
  r.h[1] = __float22bfloat162_rn(make_float2(v.z, v.w));
  return r.u;
}

__device__ __forceinline__ bf16x8 pack8(const float* v) {
  union { bf16x8 x; __hip_bfloat162 h[4]; } u;
#pragma unroll
  for (int i = 0; i < 4; ++i)
    u.h[i] = __float22bfloat162_rn(make_float2(v[2 * i], v[2 * i + 1]));
  return u.x;
}

__device__ __forceinline__ unsigned short f2bf(float x) {
  unsigned int u = __float_as_uint(x);
  u += 0x7fffu + ((u >> 16) & 1u);
  return (unsigned short)(u >> 16);
}

// ---------------- Kernel 1: dots + norms + softmax -> attn^T bf16 ----------------
// grid = B*4 (t-tiles of 16), block = 256 (4 waves; waves 0..2 = r-tiles)
__global__ __launch_bounds__(256) void scan_attn(
    const float* __restrict__ img, const float* __restrict__ cap,
    unsigned short* __restrict__ attnw) {
  __shared__ unsigned short scap[16 * LSTR];   // [t-local][d-chunk] bf16
  __shared__ unsigned short simg[48 * LSTR];   // [r][d-chunk] bf16, rows 36..47 zero
  __shared__ float sdots[16][52];
  __shared__ float sni[KPAD];
  __shared__ float snc[16];

  const int tid  = threadIdx.x;
  const int lane = tid & 63;
  const int wave = tid >> 6;
  const int fm   = lane & 15;
  const int kq   = lane >> 4;
  const int b    = blockIdx.x >> 2;
  const int t0   = (blockIdx.x & 3) << 4;

  const float* capb = cap + (size_t)b * TTOK * DDIM;
  const float* imgb = img + (size_t)b * RREG * DDIM;

  // zero img LDS rows 36..47 (12*LSTR = 3168 shorts = 792 ushort4 slots)
  {
    ushort4 zz; zz.x = 0; zz.y = 0; zz.z = 0; zz.w = 0;
    for (int i = tid; i < 792; i += 256)
      *(ushort4*)(simg + 36 * LSTR + i * 4) = zz;
  }

  // staging ownership: u = row (0..15 cap, 16..51 img), q = quarter of a 64B line
  const int u = tid >> 2;
  const int q = tid & 3;
  const bool active = (u < 52);
  const bool is_cap = (u < 16);
  const float* srcrow = is_cap ? (capb + (size_t)(t0 + u) * DDIM)
                               : (imgb + (size_t)(active ? (u - 16) : 0) * DDIM);
  unsigned short* dstrow = is_cap ? (scap + u * LSTR) : (simg + (u - 16) * LSTR);

  float nrm = 0.f;
  f32x4 acc = {0.f, 0.f, 0.f, 0.f};

  for (int c = 0; c < 4; ++c) {
    if (c) __syncthreads();   // protect LDS from overwrite while previous chunk in use
    if (active) {
#pragma unroll
      for (int s = 0; s < 16; ++s) {
        const int col = s * 16 + q * 4;   // float index within chunk
        float4 v = *(const float4*)(srcrow + c * CHUNK + col);
        nrm += sq4(v);
        *(ushort4*)(dstrow + col) = cvt4(v);
      }
    }
    __syncthreads();
    if (wave < 3) {
      // A[m=t][k=d] from scap row fm; B[k=d][n=r] from simg row (wave*16+fm)
      const unsigned short* arow = scap + fm * LSTR + kq * 8;
      const unsigned short* brow = simg + (wave * 16 + fm) * LSTR + kq * 8;
#pragma unroll
      for (int ks = 0; ks < 8; ++ks) {
        bf16x8 av = *(const bf16x8*)(arow + ks * 32);
        bf16x8 bv = *(const bf16x8*)(brow + ks * 32);
        acc = __builtin_amdgcn_mfma_f32_16x16x32_bf16(av, bv, acc, 0, 0, 0);
      }
    }
  }

  // exact fp32 norms: reduce the 4 owners of each row
  nrm += __shfl_xor(nrm, 1);
  nrm += __shfl_xor(nrm, 2);
  if (active && q == 0) {
    if (is_cap) snc[u] = sqrtf(nrm);
    else        sni[u - 16] = sqrtf(nrm);
  }
  // D tile: row(t-local)=kq*4+i, col(r-local)=fm
  if (wave < 3) {
#pragma unroll
    for (int i = 0; i < 4; ++i)
      sdots[kq * 4 + i][wave * 16 + fm] = acc[i];
  }
  __syncthreads();

  // softmax over r for 16 tokens; one thread per token
  if (tid < 16) {
    const float cnv = snc[tid];
    float sc[RREG];
    float mx = -1e30f;
#pragma unroll
    for (int rr = 0; rr < RREG; ++rr) {
      float dnm = fmaxf(sni[rr] * cnv, 1e-8f);
      float v = sdots[tid][rr] / dnm;
      sc[rr] = v;
      mx = fmaxf(mx, v);
    }
    float sum = 0.f;
#pragma unroll
    for (int rr = 0; rr < RREG; ++rr) {
      float ev = __expf(sc[rr] - mx);
      sc[rr] = ev;
      sum += ev;
    }
    const float rinv = 1.f / sum;
    unsigned short* arow = attnw + ((size_t)b * TTOK + t0 + tid) * KPAD;
#pragma unroll
    for (int r0 = 0; r0 < RREG; r0 += 4) {
      ushort4 p;
      p.x = f2bf(sc[r0 + 0] * rinv);
      p.y = f2bf(sc[r0 + 1] * rinv);
      p.z = f2bf(sc[r0 + 2] * rinv);
      p.w = f2bf(sc[r0 + 3] * rinv);
      *(ushort4*)(arow + r0) = p;
    }
    ushort4 zz; zz.x = 0; zz.y = 0; zz.z = 0; zz.w = 0;
    *(ushort4*)(arow + 36) = zz;
    *(ushort4*)(arow + 40) = zz;
    *(ushort4*)(arow + 44) = zz;
  }
}

// ---------------- Kernel 2: out = attn^T(64x48) . img(48x1024) ----------------
// grid = B*4 (d-chunks of 256), block = 256 (4 waves = 4 t-tiles); no LDS, no barriers
__global__ __launch_bounds__(256) void scan_out(
    const float* __restrict__ img, const unsigned short* __restrict__ attnw,
    float* __restrict__ out) {
  const int tid  = threadIdx.x;
  const int lane = tid & 63;
  const int wave = tid >> 6;        // t-tile 0..3
  const int fm   = lane & 15;
  const int kq   = lane >> 4;
  const int b    = blockIdx.x >> 2;
  const int d0   = (blockIdx.x & 3) << 8;

  const float* imgb = img + (size_t)b * RREG * DDIM;
  const unsigned short* attb = attnw + (size_t)b * TTOK * KPAD;
  float* outb = out + (size_t)b * TTOK * DDIM;

  const unsigned short* ap = attb + (wave * 16 + fm) * KPAD;
  bf16x8 zf = {0, 0, 0, 0, 0, 0, 0, 0};
  bf16x8 af0 = *(const bf16x8*)(ap + kq * 8);
  bf16x8 af1 = zf;
  if (kq < 2) af1 = *(const bf16x8*)(ap + 32 + kq * 8);

  for (int s = 0; s < 16; ++s) {
    const int d = d0 + s * 16 + fm;
    float v[8];
#pragma unroll
    for (int j = 0; j < 8; ++j) v[j] = imgb[(kq * 8 + j) * DDIM + d];
    bf16x8 bf0 = pack8(v);
    bf16x8 bf1 = zf;
    if (kq == 0) {
      float w[8];
#pragma unroll
      for (int j = 0; j < 4; ++j) w[j] = imgb[(32 + j) * DDIM + d];
#pragma unroll
      for (int j = 4; j < 8; ++j) w[j] = 0.f;
      bf1 = pack8(w);
    }
    f32x4 o = {0.f, 0.f, 0.f, 0.f};
    o = __builtin_amdgcn_mfma_f32_16x16x32_bf16(af0, bf0, o, 0, 0, 0);
    o = __builtin_amdgcn_mfma_f32_16x16x32_bf16(af1, bf1, o, 0, 0, 0);
    float* op = outb + (wave * 16 + kq * 4) * DDIM + d;
#pragma unroll
    for (int i = 0; i < 4; ++i) op[i * DDIM] = o[i];
  }
}

extern "C" void kernel_launch(void* const* d_in, const int* in_sizes, int n_in,
                              void* d_out, int out_size, void* d_ws, size_t ws_size,
                              hipStream_t stream) {
  const float* img = (const float*)d_in[0];   // (256, 36, 1024) fp32
  const float* cap = (const float*)d_in[1];   // (256, 64, 1024) fp32
  float* out = (float*)d_out;                 // (256, 64, 1024) fp32
  unsigned short* attnw = (unsigned short*)d_ws;  // attn^T bf16 [B][64][48] = 1.5 MB

  scan_attn<<<dim3(1024), dim3(256), 0, stream>>>(img, cap, attnw);
  scan_out<<<dim3(1024), dim3(256), 0, stream>>>(img, attnw, out);
}